// Round 11
// baseline (89.373 us; speedup 1.0000x reference)
//
#include <hip/hip_runtime.h>

// ROI pooling — DIAGNOSTIC ROUND (R11): K2 repeats its full sweep 3x so the
// pool kernel rises above the harness fill kernels in the rocprof top-5 and
// we finally get its counters (FETCH/WRITE/VALUBusy/Occupancy). Stores are
// identical across reps -> output unchanged and deterministic.
//
// Base structure = R9/R10 (46.4 us best): ylo counting sort (K1), 1750 blocks
// x 4 waves x 2 sorted pairs, bijective XCD-chunked swizzle, NT stores.

typedef float f32x4 __attribute__((ext_vector_type(4)));

// ---- K1: counting sort of pairs by ylo into perm (d_ws) ---------------------
__global__ __launch_bounds__(1024) void roi_sort_kernel(
    const int* __restrict__ rois, int R, int* __restrict__ perm)
{
    __shared__ int cnt[256];
    const int tid   = threadIdx.x;
    const int pairs = R * 7;

    if (tid < 256) cnt[tid] = 0;
    __syncthreads();

    for (int p = tid; p < pairs; p += 1024) {
        const int r  = p / 7;
        const int py = p - r * 7;
        const int y  = rois[4 * r + 1];
        const int h  = rois[4 * r + 3];
        const float ty = ((float)py + 0.5f) * ((float)h / 7.0f) - 0.5f;
        const int  iy  = (int)floorf(ty);
        const int  ylo = min(max(iy, 0), h - 1) + y;   // in [0,199]
        atomicAdd(&cnt[ylo], 1);
    }
    __syncthreads();

    // exclusive scan over 256 bins: wave 0, 4 bins/lane + shfl_up scan
    if (tid < 64) {
        const int b  = tid << 2;
        const int v0 = cnt[b], v1 = cnt[b + 1], v2 = cnt[b + 2], v3 = cnt[b + 3];
        const int tot = v0 + v1 + v2 + v3;
        int inc = tot;
        #pragma unroll
        for (int off = 1; off < 64; off <<= 1) {
            const int t = __shfl_up(inc, off);
            if (tid >= off) inc += t;
        }
        const int excl = inc - tot;
        cnt[b]     = excl;
        cnt[b + 1] = excl + v0;
        cnt[b + 2] = excl + v0 + v1;
        cnt[b + 3] = excl + v0 + v1 + v2;
    }
    __syncthreads();

    for (int p = tid; p < pairs; p += 1024) {
        const int r  = p / 7;
        const int py = p - r * 7;
        const int y  = rois[4 * r + 1];
        const int h  = rois[4 * r + 3];
        const float ty = ((float)py + 0.5f) * ((float)h / 7.0f) - 0.5f;
        const int  iy  = (int)floorf(ty);
        const int  ylo = min(max(iy, 0), h - 1) + y;
        const int  pos = atomicAdd(&cnt[ylo], 1);
        perm[pos] = p;
    }
}

// ---- K2: 2 sorted pairs per wave, repeated nreps times (diagnostic) ---------
__global__ __launch_bounds__(256, 7) void roi_pool_kernel(
    const float* __restrict__ img,
    const int*   __restrict__ rois,
    const int*   __restrict__ perm,
    float*       __restrict__ out,
    int npairs, int nreps)
{
    constexpr int P = 7;
    constexpr int C = 256;
    constexpr int W = 200;

    // bijective XCD-chunk swizzle (m204): each XCD owns a contiguous chunk
    const int nwg  = gridDim.x;
    const int q    = nwg >> 3;
    const int rr   = nwg & 7;
    const int xcd  = blockIdx.x & 7;
    const int base = (xcd < rr) ? xcd * (q + 1) : rr * (q + 1) + (xcd - rr) * q;
    const int bid  = base + (blockIdx.x >> 3);

    const int wave = threadIdx.x >> 6;
    const int c    = (threadIdx.x & 63) << 2;      // 4 channels/lane

    for (int rep = 0; rep < nreps; ++rep) {
        for (int k = 0; k < 2; ++k) {
            const int pidx = bid * 8 + wave * 2 + k;
            if (pidx >= npairs) continue;

            const int p  = perm[pidx];
            const int r  = p / 7;
            const int py = p - r * 7;

            const int x = rois[4 * r + 0];
            const int y = rois[4 * r + 1];
            const int w = rois[4 * r + 2];
            const int h = rois[4 * r + 3];

            const float ty = ((float)py + 0.5f) * ((float)h / (float)P) - 0.5f;
            const float fy = floorf(ty);
            const float wy = ty - fy;
            const int   iy = (int)fy;
            const int   ylo = min(max(iy,     0), h - 1) + y;
            const int   yhi = min(max(iy + 1, 0), h - 1) + y;

            const float* row0 = img + (long)ylo * W * C + c;
            const float* row1 = img + (long)yhi * W * C + c;
            const float  sx   = (float)w / (float)P;

            float* out_row = out + ((long)r * P + py) * P * C + c;

            #pragma unroll
            for (int px = 0; px < P; ++px) {
                const float tx = ((float)px + 0.5f) * sx - 0.5f;
                const float fx = floorf(tx);
                const float wx = tx - fx;
                const int   ix = (int)fx;
                const int   xlo = min(max(ix,     0), w - 1) + x;
                const int   xhi = min(max(ix + 1, 0), w - 1) + x;

                const f32x4 v00 = *(const f32x4*)(row0 + xlo * C);
                const f32x4 v01 = *(const f32x4*)(row0 + xhi * C);
                const f32x4 v10 = *(const f32x4*)(row1 + xlo * C);
                const f32x4 v11 = *(const f32x4*)(row1 + xhi * C);

                const f32x4 top = v00 + (v01 - v00) * wx;
                const f32x4 bot = v10 + (v11 - v10) * wx;
                const f32x4 res = top + (bot - top) * wy;

                __builtin_nontemporal_store(res, (f32x4*)(out_row + px * C));
            }
        }
        // keep reps observable: forbid store/load elimination across reps
        asm volatile("" ::: "memory");
    }
}

extern "C" void kernel_launch(void* const* d_in, const int* in_sizes, int n_in,
                              void* d_out, int out_size, void* d_ws, size_t ws_size,
                              hipStream_t stream) {
    const float* img  = (const float*)d_in[0];
    const int*   rois = (const int*)d_in[1];
    float*       out  = (float*)d_out;
    int*         perm = (int*)d_ws;

    const int R      = in_sizes[1] / 4;   // 2000
    const int npairs = R * 7;             // 14000
    const int blocks = (npairs + 7) / 8;  // 1750

    roi_sort_kernel<<<1, 1024, 0, stream>>>(rois, R, perm);
    roi_pool_kernel<<<blocks, 256, 0, stream>>>(img, rois, perm, out, npairs, 3);
}

// Round 13
// 46.063 us; speedup vs baseline: 1.9402x; 1.9402x over previous
//
#include <hip/hip_runtime.h>

// ROI pooling: bilinear resize each (h,w) crop to 7x7 over 256 channels.
// img: (200,200,256) f32 NHWC; rois: (2000,4) int32 (x,y,w,h); out: (2000,7,7,256) f32.
//
// R13 = R12 with the x-offset bug fixed (xls/xhs must include the ROI's x).
// R11 diagnostics: K2 is L2-gather-latency-bound (image L2-resident, FETCH=33MB,
// 2.75 TB/s vs 6.6 wall, VGPR=36 -> ~6 loads in flight). Fix: phase-split
// loads per pair (all 14 row0 loads batched, then all 14 row1), with
// __launch_bounds__(256,4) raising the VGPR cap to 128.
//  K1: ylo counting sort (200 bins, wave-parallel scan).
//  K2: 1750 blocks x 4 waves x 2 sorted pairs (14000 = 1750*8, exact),
//      bijective XCD-chunked swizzle, NT stores.

typedef float f32x4 __attribute__((ext_vector_type(4)));

// ---- K1: counting sort of pairs by ylo into perm (d_ws) ---------------------
__global__ __launch_bounds__(1024) void roi_sort_kernel(
    const int* __restrict__ rois, int R, int* __restrict__ perm)
{
    __shared__ int cnt[256];
    const int tid   = threadIdx.x;
    const int pairs = R * 7;

    if (tid < 256) cnt[tid] = 0;
    __syncthreads();

    for (int p = tid; p < pairs; p += 1024) {
        const int r  = p / 7;
        const int py = p - r * 7;
        const int y  = rois[4 * r + 1];
        const int h  = rois[4 * r + 3];
        const float ty = ((float)py + 0.5f) * ((float)h / 7.0f) - 0.5f;
        const int  iy  = (int)floorf(ty);
        const int  ylo = min(max(iy, 0), h - 1) + y;   // in [0,199]
        atomicAdd(&cnt[ylo], 1);
    }
    __syncthreads();

    if (tid < 64) {   // exclusive scan over 256 bins (wave 0)
        const int b  = tid << 2;
        const int v0 = cnt[b], v1 = cnt[b + 1], v2 = cnt[b + 2], v3 = cnt[b + 3];
        const int tot = v0 + v1 + v2 + v3;
        int inc = tot;
        #pragma unroll
        for (int off = 1; off < 64; off <<= 1) {
            const int t = __shfl_up(inc, off);
            if (tid >= off) inc += t;
        }
        const int excl = inc - tot;
        cnt[b]     = excl;
        cnt[b + 1] = excl + v0;
        cnt[b + 2] = excl + v0 + v1;
        cnt[b + 3] = excl + v0 + v1 + v2;
    }
    __syncthreads();

    for (int p = tid; p < pairs; p += 1024) {
        const int r  = p / 7;
        const int py = p - r * 7;
        const int y  = rois[4 * r + 1];
        const int h  = rois[4 * r + 3];
        const float ty = ((float)py + 0.5f) * ((float)h / 7.0f) - 0.5f;
        const int  iy  = (int)floorf(ty);
        const int  ylo = min(max(iy, 0), h - 1) + y;
        const int  pos = atomicAdd(&cnt[ylo], 1);
        perm[pos] = p;
    }
}

// ---- K2: phase-split deep-batched loads, 2 pairs per wave -------------------
__global__ __launch_bounds__(256, 4) void roi_pool_kernel(
    const float* __restrict__ img,
    const int*   __restrict__ rois,
    const int*   __restrict__ perm,
    float*       __restrict__ out)
{
    constexpr int P = 7;
    constexpr int C = 256;
    constexpr int W = 200;

    // bijective XCD-chunk swizzle (m204): each XCD owns a contiguous chunk
    const int nwg  = gridDim.x;
    const int q    = nwg >> 3;
    const int rr   = nwg & 7;
    const int xcd  = blockIdx.x & 7;
    const int base = (xcd < rr) ? xcd * (q + 1) : rr * (q + 1) + (xcd - rr) * q;
    const int bid  = base + (blockIdx.x >> 3);

    const int wave = threadIdx.x >> 6;
    const int c    = (threadIdx.x & 63) << 2;      // 4 channels/lane

    #pragma unroll
    for (int k = 0; k < 2; ++k) {
        const int pidx = bid * 8 + wave * 2 + k;   // grid exactly covers 14000

        const int p  = perm[pidx];
        const int r  = p / 7;
        const int py = p - r * 7;

        const int x = rois[4 * r + 0];
        const int y = rois[4 * r + 1];
        const int w = rois[4 * r + 2];
        const int h = rois[4 * r + 3];

        const float ty = ((float)py + 0.5f) * ((float)h / (float)P) - 0.5f;
        const float fy = floorf(ty);
        const float wy = ty - fy;
        const int   iy = (int)fy;
        const int   ylo = min(max(iy,     0), h - 1) + y;
        const int   yhi = min(max(iy + 1, 0), h - 1) + y;

        const float* row0 = img + (long)ylo * W * C + c;
        const float* row1 = img + (long)yhi * W * C + c;
        const float  sx   = (float)w / (float)P;

        float wxs[P];
        int   xls[P], xhs[P];
        #pragma unroll
        for (int px = 0; px < P; ++px) {
            const float tx = ((float)px + 0.5f) * sx - 0.5f;
            const float fx = floorf(tx);
            wxs[px] = tx - fx;
            const int ix = (int)fx;
            xls[px] = (min(max(ix,     0), w - 1) + x) * C;   // + x: ROI offset!
            xhs[px] = (min(max(ix + 1, 0), w - 1) + x) * C;
        }

        // ---- phase A: all 14 row0 loads in flight, then horizontal interp --
        f32x4 a0[P], a1[P];
        #pragma unroll
        for (int px = 0; px < P; ++px) {
            a0[px] = *(const f32x4*)(row0 + xls[px]);
            a1[px] = *(const f32x4*)(row0 + xhs[px]);
        }
        f32x4 top[P];
        #pragma unroll
        for (int px = 0; px < P; ++px)
            top[px] = a0[px] + (a1[px] - a0[px]) * wxs[px];

        // ---- phase B: all 14 row1 loads in flight, interp + store ----------
        f32x4 b0[P], b1[P];
        #pragma unroll
        for (int px = 0; px < P; ++px) {
            b0[px] = *(const f32x4*)(row1 + xls[px]);
            b1[px] = *(const f32x4*)(row1 + xhs[px]);
        }

        float* out_row = out + ((long)r * P + py) * P * C + c;
        #pragma unroll
        for (int px = 0; px < P; ++px) {
            const f32x4 bot = b0[px] + (b1[px] - b0[px]) * wxs[px];
            const f32x4 res = top[px] + (bot - top[px]) * wy;
            __builtin_nontemporal_store(res, (f32x4*)(out_row + px * C));
        }
    }
}

extern "C" void kernel_launch(void* const* d_in, const int* in_sizes, int n_in,
                              void* d_out, int out_size, void* d_ws, size_t ws_size,
                              hipStream_t stream) {
    const float* img  = (const float*)d_in[0];
    const int*   rois = (const int*)d_in[1];
    float*       out  = (float*)d_out;
    int*         perm = (int*)d_ws;

    const int R      = in_sizes[1] / 4;   // 2000
    const int npairs = R * 7;             // 14000
    const int blocks = npairs / 8;        // 1750: 4 waves x 2 pairs, exact

    roi_sort_kernel<<<1, 1024, 0, stream>>>(rois, R, perm);
    roi_pool_kernel<<<blocks, 256, 0, stream>>>(img, rois, perm, out);
}